// Round 3
// baseline (121.801 us; speedup 1.0000x reference)
//
#include <hip/hip_runtime.h>
#include <hip/hip_bf16.h>
#include <stdint.h>

typedef __attribute__((ext_vector_type(8))) short short8;
typedef __attribute__((ext_vector_type(4))) float f32x4;

#define DD 512
#define TT 16   // tokens per block (1 wave)
#define TN 4096 // T
#define NB 8    // B

__device__ __forceinline__ unsigned short f2bf(float f){
  uint32_t u = __float_as_uint(f);
  u += 0x7FFFu + ((u >> 16) & 1u);
  return (unsigned short)(u >> 16);
}
__device__ __forceinline__ float bf2f(unsigned short h){
  return __uint_as_float(((uint32_t)h) << 16);
}

// ---------------- prep kernels (quad-split dots) ----------------

__global__ void prep_spk(const float* __restrict__ se, const float* __restrict__ We,
                         const float* __restrict__ be, const float* __restrict__ spos,
                         float* __restrict__ spk){
  int idx = blockIdx.x * 256 + threadIdx.x;   // 65536
  int sub = idx & 3; int out = idx >> 2;
  int b = out & 7, od = out >> 3;
  const float* wr = We + (size_t)od * DD + sub * 4;
  const float* sb = se + b * DD + sub * 4;
  float acc = 0.f;
#pragma unroll 8
  for (int i = 0; i < 32; i++){
    float4 w = *(const float4*)(wr + i * 16);
    float4 x = *(const float4*)(sb + i * 16);
    acc += w.x * x.x + w.y * x.y + w.z * x.z + w.w * x.w;
  }
  acc += __shfl_xor(acc, 1); acc += __shfl_xor(acc, 2);
  if (sub == 0) spk[b * 2048 + od] = fmaxf(acc + be[od], 0.f) + spos[od];
}

__global__ void prep_kv(const float* __restrict__ spk, const float* __restrict__ Wk,
                        const float* __restrict__ bk, const float* __restrict__ Wv,
                        const float* __restrict__ bv, float* __restrict__ kb,
                        float* __restrict__ vb){
  int idx = blockIdx.x * 256 + threadIdx.x;   // 65536
  int sub = idx & 3; int out = idx >> 2;
  int hd = out >> 5; int r = out & 31; int b = r >> 2, s = r & 3;
  const float* sp  = spk + (b * 4 + s) * DD + sub * 4;
  const float* wkr = Wk + (size_t)hd * DD + sub * 4;
  const float* wvr = Wv + (size_t)hd * DD + sub * 4;
  float ak = 0.f, av = 0.f;
#pragma unroll 8
  for (int i = 0; i < 32; i++){
    float4 x  = *(const float4*)(sp + i * 16);
    float4 wk = *(const float4*)(wkr + i * 16);
    float4 wv = *(const float4*)(wvr + i * 16);
    ak += x.x * wk.x + x.y * wk.y + x.z * wk.z + x.w * wk.w;
    av += x.x * wv.x + x.y * wv.y + x.z * wv.z + x.w * wv.w;
  }
  ak += __shfl_xor(ak, 1); ak += __shfl_xor(ak, 2);
  av += __shfl_xor(av, 1); av += __shfl_xor(av, 2);
  if (sub == 0){
    kb[(b * 4 + s) * DD + hd] = ak + bk[hd];
    vb[(b * 4 + s) * DD + hd] = av + bv[hd];
  }
}

__global__ void prep_mu(const float* __restrict__ kb, const float* __restrict__ vb,
                        const float* __restrict__ Wq, const float* __restrict__ bq,
                        const float* __restrict__ Wo, const float* __restrict__ Wg1,
                        const float* __restrict__ glng, const float* __restrict__ glnb,
                        const float* __restrict__ bg1,
                        unsigned short* __restrict__ mB, unsigned short* __restrict__ uT,
                        float* __restrict__ cArr, unsigned short* __restrict__ wg1B,
                        float* __restrict__ e1, float* __restrict__ e2){
  int idx = blockIdx.x * 256 + threadIdx.x;     // 328064 total
  if (idx < 131072){
    int d = idx & 511; int j = (idx >> 9) & 31; int b = idx >> 14;
    int h = j >> 2, s = j & 3;
    const float* kr = kb + (b * 4 + s) * DD + h * 64;
    const float* wq = Wq + (size_t)(h * 64) * DD + d;
    float acc = 0.f;
#pragma unroll 16
    for (int dh = 0; dh < 64; dh++) acc += wq[(size_t)dh * DD] * kr[dh];
    mB[idx] = f2bf(acc);
  } else if (idx < 262144){
    int t = idx - 131072;
    int j = t & 31; int d = (t >> 5) & 511; int b = t >> 14;
    int h = j >> 2, s = j & 3;
    const float* vr = vb + (b * 4 + s) * DD + h * 64;
    const float* wo = Wo + (size_t)d * DD + h * 64;
    float acc = 0.f;
#pragma unroll 8
    for (int dh = 0; dh < 64; dh += 4){
      float4 v4 = *(const float4*)(vr + dh);
      float4 w4 = *(const float4*)(wo + dh);
      acc += v4.x * w4.x + v4.y * w4.y + v4.z * w4.z + v4.w * w4.w;
    }
    uT[b * 16384 + d * 32 + j] = f2bf(acc);
  } else if (idx < 327680){
    int t = idx - 262144;
    wg1B[t] = f2bf(Wg1[t] * glng[t & 511]);
  } else if (idx < 327936){
    int t = idx - 327680; int j = t & 31, b = t >> 5;
    int h = j >> 2, s = j & 3;
    const float* kr = kb + (b * 4 + s) * DD + h * 64;
    const float* bqp = bq + h * 64;
    float acc = 0.f;
    for (int dh = 0; dh < 64; dh++) acc += bqp[dh] * kr[dh];
    cArr[b * 32 + j] = acc;
  } else if (idx < 328064){
    int col = idx - 327936;
    const float* wr = Wg1 + (size_t)col * DD;
    float a1 = 0.f, a2 = 0.f;
    for (int d = 0; d < DD; d += 4){
      float4 w  = *(const float4*)(wr + d);
      float4 gm = *(const float4*)(glng + d);
      float4 bt = *(const float4*)(glnb + d);
      a1 += w.x * gm.x + w.y * gm.y + w.z * gm.z + w.w * gm.w;
      a2 += w.x * bt.x + w.y * bt.y + w.z * bt.z + w.w * bt.w;
    }
    e1[col] = a1; e2[col] = a2 + bg1[col];
  }
}

// ---------------- main fused kernel: 1 wave, 16 tokens, register A-frags ----------------

__global__ __launch_bounds__(64, 3) void fused_main(
    const float* __restrict__ xin,
    const float* __restrict__ e1v, const float* __restrict__ e2v,
    const float* __restrict__ wg2v, const float* __restrict__ bg2v,
    const float* __restrict__ bov,  const float* __restrict__ lng, const float* __restrict__ lnb,
    const unsigned short* __restrict__ mB,
    const unsigned short* __restrict__ uTB,
    const float* __restrict__ cArr,
    const unsigned short* __restrict__ wg1B,
    float* __restrict__ outF, float* __restrict__ outAW, float* __restrict__ outG)
{
  __shared__ __align__(16) unsigned short Wl[TT * 32];   // 1 KB softmax weights

  const int lane = threadIdx.x;
  const int r16 = lane & 15;
  const int kg  = lane >> 4;
  const int bb  = blockIdx.x >> 8;            // batch
  const int t0  = (blockIdx.x & 255) << 4;    // token tile base
  const size_t rowbase = (size_t)bb * TN + t0;

  // ---- Phase 0: load x row r16 directly in A-fragment layout; LN stats ----
  short8 af[16];
  float mu, rs;
  {
    const float* xr = xin + (rowbase + r16) * DD + kg * 8;
    float s = 0.f, q = 0.f;
#pragma unroll
    for (int kt = 0; kt < 16; kt++){
      float4 v0 = *(const float4*)(xr + kt * 32);
      float4 v1 = *(const float4*)(xr + kt * 32 + 4);
      float xv[8] = {v0.x, v0.y, v0.z, v0.w, v1.x, v1.y, v1.z, v1.w};
      short8 pk;
#pragma unroll
      for (int j = 0; j < 8; j++){
        s += xv[j]; q += xv[j] * xv[j];
        pk[j] = (short)f2bf(xv[j]);
      }
      af[kt] = pk;
    }
    s += __shfl_xor(s, 16); s += __shfl_xor(s, 32);
    q += __shfl_xor(q, 16); q += __shfl_xor(q, 32);
    mu = s * (1.f / DD);
    rs = rsqrtf(q * (1.f / DD) - mu * mu + 1e-5f);
  }

  // ---- Phase 1: scores + gate GEMM from register A-frags ----
  f32x4 sa0 = {0.f,0.f,0.f,0.f}, sa1 = {0.f,0.f,0.f,0.f};
  f32x4 gacc[8];
#pragma unroll
  for (int nt = 0; nt < 8; nt++){ f32x4 z = {0.f,0.f,0.f,0.f}; gacc[nt] = z; }
  {
    const unsigned short* mb = mB + (size_t)bb * 32 * DD;
#pragma unroll
    for (int kt = 0; kt < 16; kt++){
      const int kc = kt * 32 + kg * 8;
      short8 b0 = *(const short8*)&mb[r16 * DD + kc];
      short8 b1 = *(const short8*)&mb[(r16 + 16) * DD + kc];
      sa0 = __builtin_amdgcn_mfma_f32_16x16x32_bf16(af[kt], b0, sa0, 0, 0, 0);
      sa1 = __builtin_amdgcn_mfma_f32_16x16x32_bf16(af[kt], b1, sa1, 0, 0, 0);
#pragma unroll
      for (int nt = 0; nt < 8; nt++){
        short8 wf = *(const short8*)&wg1B[(size_t)(nt * 16 + r16) * DD + kc];
        gacc[nt] = __builtin_amdgcn_mfma_f32_16x16x32_bf16(wf, af[kt], gacc[nt], 0, 0, 0);
      }
    }
  }

  // softmax epilogue: thread owns tokens kg*4+r at head-idx j=r16
  {
    const float c0v = cArr[bb * 32 + r16];
    const float c1v = cArr[bb * 32 + r16 + 16];
#pragma unroll
    for (int r = 0; r < 4; r++){
      float s0 = (sa0[r] + c0v) * 0.125f;
      float s1 = (sa1[r] + c1v) * 0.125f;
      float mx0 = fmaxf(s0, __shfl_xor(s0, 1)); mx0 = fmaxf(mx0, __shfl_xor(mx0, 2));
      float mx1 = fmaxf(s1, __shfl_xor(s1, 1)); mx1 = fmaxf(mx1, __shfl_xor(mx1, 2));
      float e0 = __expf(s0 - mx0), e1x = __expf(s1 - mx1);
      float d0 = e0;  d0 += __shfl_xor(d0, 1); d0 += __shfl_xor(d0, 2);
      float d1 = e1x; d1 += __shfl_xor(d1, 1); d1 += __shfl_xor(d1, 2);
      float w0 = e0 / d0, w1 = e1x / d1;
      float t = w0 + w1; t += __shfl_xor(t, 4); t += __shfl_xor(t, 8); t *= 0.125f;
      const int rw = kg * 4 + r;
      if ((lane & 12) == 0) outAW[(rowbase + rw) * 4 + (lane & 3)] = t;
      Wl[rw * 32 + r16]      = f2bf(w0);
      Wl[rw * 32 + r16 + 16] = f2bf(w1);
    }
  }

  // gate epilogue: thread owns token r16 (mu/rs in registers)
  float g_reg;
  {
    float part = 0.f;
#pragma unroll
    for (int nt = 0; nt < 8; nt++){
      const int c4 = nt * 16 + kg * 4;
      float4 e1c = *(const float4*)(e1v + c4);
      float4 e2c = *(const float4*)(e2v + c4);
      float4 w2c = *(const float4*)(wg2v + c4);
      float e1a[4] = {e1c.x, e1c.y, e1c.z, e1c.w};
      float e2a[4] = {e2c.x, e2c.y, e2c.z, e2c.w};
      float w2a[4] = {w2c.x, w2c.y, w2c.z, w2c.w};
#pragma unroll
      for (int r = 0; r < 4; r++){
        float gv = rs * (gacc[nt][r] - mu * e1a[r]) + e2a[r];
        gv = fmaxf(gv, 0.f);
        part += gv * w2a[r];
      }
    }
    part += __shfl_xor(part, 16); part += __shfl_xor(part, 32);
    g_reg = 1.f / (1.f + __expf(-(part + bg2v[0])));
    if (kg == 0) outG[rowbase + r16] = g_reg;
  }
  __syncthreads();

  // ---- Phase 3+4: ATT (token=r16 col), residual from fp32 x reload, LN, store ----
  {
    short8 aw = *(const short8*)&Wl[r16 * 32 + kg * 8];
    const unsigned short* ub = uTB + (size_t)bb * DD * 32;
    const float* xrp = xin + (rowbase + r16) * DD;
    float* orp = outF + (rowbase + r16) * DD;
    short8 ybf[16];
    float psum = 0.f, psq = 0.f;
#pragma unroll
    for (int nc = 0; nc < 4; nc++){
      f32x4 acc[8];
#pragma unroll
      for (int nt = 0; nt < 8; nt++){ f32x4 z = {0.f,0.f,0.f,0.f}; acc[nt] = z; }
#pragma unroll
      for (int nt = 0; nt < 8; nt++){
        const int n0 = nc * 128 + nt * 16;
        short8 uf = *(const short8*)&ub[(n0 + r16) * 32 + kg * 8];
        acc[nt] = __builtin_amdgcn_mfma_f32_16x16x32_bf16(uf, aw, acc[nt], 0, 0, 0);
      }
#pragma unroll
      for (int nt = 0; nt < 8; nt++){
        const int c4 = nc * 128 + nt * 16 + kg * 4;
        float4 xv4 = *(const float4*)(xrp + c4);
        float4 bo4 = *(const float4*)(bov + c4);
        float xa[4] = {xv4.x, xv4.y, xv4.z, xv4.w};
        float ba[4] = {bo4.x, bo4.y, bo4.z, bo4.w};
#pragma unroll
        for (int r = 0; r < 4; r++){
          float y = xa[r] + g_reg * (acc[nt][r] + ba[r]);
          psum += y; psq += y * y;
          ybf[nc * 4 + (nt >> 1)][(nt & 1) * 4 + r] = (short)f2bf(y);
        }
      }
    }
    psum += __shfl_xor(psum, 16); psum += __shfl_xor(psum, 32);
    psq  += __shfl_xor(psq, 16);  psq  += __shfl_xor(psq, 32);
    const float mu2 = psum * (1.f / DD);
    const float rs2 = rsqrtf(psq * (1.f / DD) - mu2 * mu2 + 1e-5f);
#pragma unroll
    for (int nc = 0; nc < 4; nc++){
#pragma unroll
      for (int nt = 0; nt < 8; nt++){
        const int c4 = nc * 128 + nt * 16 + kg * 4;
        float4 lg4 = *(const float4*)(lng + c4);
        float4 lb4 = *(const float4*)(lnb + c4);
        float la[4] = {lg4.x, lg4.y, lg4.z, lg4.w};
        float ba[4] = {lb4.x, lb4.y, lb4.z, lb4.w};
        float4 o;
        float ov[4];
#pragma unroll
        for (int r = 0; r < 4; r++){
          float y = bf2f((unsigned short)ybf[nc * 4 + (nt >> 1)][(nt & 1) * 4 + r]);
          ov[r] = (y - mu2) * rs2 * la[r] + ba[r];
        }
        o.x = ov[0]; o.y = ov[1]; o.z = ov[2]; o.w = ov[3];
        *(float4*)(orp + c4) = o;
      }
    }
  }
}

// ---------------- launch ----------------

extern "C" void kernel_launch(void* const* d_in, const int* in_sizes, int n_in,
                              void* d_out, int out_size, void* d_ws, size_t ws_size,
                              hipStream_t stream)
{
  const float* token = (const float*)d_in[0];
  const float* semb  = (const float*)d_in[1];
  const float* We    = (const float*)d_in[2];
  const float* be    = (const float*)d_in[3];
  const float* spos  = (const float*)d_in[4];
  const float* Wq    = (const float*)d_in[5];
  const float* bq    = (const float*)d_in[6];
  const float* Wk    = (const float*)d_in[7];
  const float* bk    = (const float*)d_in[8];
  const float* Wv    = (const float*)d_in[9];
  const float* bv    = (const float*)d_in[10];
  const float* Wo    = (const float*)d_in[11];
  const float* bo    = (const float*)d_in[12];
  const float* glng  = (const float*)d_in[13];
  const float* glnb  = (const float*)d_in[14];
  const float* Wg1   = (const float*)d_in[15];
  const float* bg1   = (const float*)d_in[16];
  const float* Wg2   = (const float*)d_in[17];
  const float* bg2   = (const float*)d_in[18];
  const float* lng   = (const float*)d_in[19];
  const float* lnb   = (const float*)d_in[20];

  char* ws = (char*)d_ws;
  float* e1             = (float*)(ws + 0);        // 512 B (after spk dead)
  float* e2             = (float*)(ws + 512);
  float* spk            = (float*)(ws + 0);        // 64 KB (consumed before e1/e2 written)
  float* kb             = (float*)(ws + 65536);
  float* vb             = (float*)(ws + 131072);
  unsigned short* mB    = (unsigned short*)(ws + 196608);
  unsigned short* uTB   = (unsigned short*)(ws + 458752);
  float* cArr           = (float*)(ws + 720896);
  unsigned short* wg1B  = (unsigned short*)(ws + 721920);

  float* outF  = (float*)d_out;
  float* outAW = outF + (size_t)NB * TN * DD;
  float* outG  = outAW + (size_t)NB * TN * 4;

  prep_spk<<<dim3(256), dim3(256), 0, stream>>>(semb, We, be, spos, spk);
  prep_kv<<<dim3(256), dim3(256), 0, stream>>>(spk, Wk, bk, Wv, bv, kb, vb);
  prep_mu<<<dim3(1282), dim3(256), 0, stream>>>(kb, vb, Wq, bq, Wo, Wg1, glng, glnb, bg1,
                                                mB, uTB, cArr, wg1B, e1, e2);
  fused_main<<<dim3(NB * TN / TT), dim3(64), 0, stream>>>(
      token, e1, e2, Wg2, bg2, bo, lng, lnb,
      mB, uTB, cArr, wg1B, outF, outAW, outG);
}

// Round 4
// 97.202 us; speedup vs baseline: 1.2531x; 1.2531x over previous
//
#include <hip/hip_runtime.h>
#include <hip/hip_bf16.h>
#include <stdint.h>

typedef __attribute__((ext_vector_type(8))) short short8;
typedef __attribute__((ext_vector_type(4))) float f32x4;
typedef __attribute__((ext_vector_type(2))) unsigned int uint2v;

#define DD 512
#define TT 16   // tokens per block (1 wave)
#define TN 4096 // T
#define NB 8    // B

__device__ __forceinline__ unsigned short f2bf(float f){
  uint32_t u = __float_as_uint(f);
  u += 0x7FFFu + ((u >> 16) & 1u);
  return (unsigned short)(u >> 16);
}
__device__ __forceinline__ float bf2f(unsigned short h){
  return __uint_as_float(((uint32_t)h) << 16);
}

// ---------------- prep kernels (8-way-split dots) ----------------

__global__ void prep_spk(const float* __restrict__ se, const float* __restrict__ We,
                         const float* __restrict__ be, const float* __restrict__ spos,
                         float* __restrict__ spk){
  int idx = blockIdx.x * 256 + threadIdx.x;   // 131072
  int sub = idx & 7; int out = idx >> 3;
  int b = out & 7, od = out >> 3;
  const float* wr = We + (size_t)od * DD + sub * 4;
  const float* sb = se + b * DD + sub * 4;
  float acc = 0.f;
#pragma unroll
  for (int i = 0; i < 16; i++){
    float4 w = *(const float4*)(wr + i * 32);
    float4 x = *(const float4*)(sb + i * 32);
    acc += w.x * x.x + w.y * x.y + w.z * x.z + w.w * x.w;
  }
  acc += __shfl_xor(acc, 1); acc += __shfl_xor(acc, 2); acc += __shfl_xor(acc, 4);
  if (sub == 0) spk[b * 2048 + od] = fmaxf(acc + be[od], 0.f) + spos[od];
}

__global__ void prep_kv(const float* __restrict__ spk, const float* __restrict__ Wk,
                        const float* __restrict__ bk, const float* __restrict__ Wv,
                        const float* __restrict__ bv, float* __restrict__ kb,
                        float* __restrict__ vb){
  int idx = blockIdx.x * 256 + threadIdx.x;   // 131072
  int sub = idx & 7; int out = idx >> 3;
  int hd = out >> 5; int r = out & 31; int b = r >> 2, s = r & 3;
  const float* sp  = spk + (b * 4 + s) * DD + sub * 4;
  const float* wkr = Wk + (size_t)hd * DD + sub * 4;
  const float* wvr = Wv + (size_t)hd * DD + sub * 4;
  float ak = 0.f, av = 0.f;
#pragma unroll
  for (int i = 0; i < 16; i++){
    float4 x  = *(const float4*)(sp + i * 32);
    float4 wk = *(const float4*)(wkr + i * 32);
    float4 wv = *(const float4*)(wvr + i * 32);
    ak += x.x * wk.x + x.y * wk.y + x.z * wk.z + x.w * wk.w;
    av += x.x * wv.x + x.y * wv.y + x.z * wv.z + x.w * wv.w;
  }
  ak += __shfl_xor(ak, 1); ak += __shfl_xor(ak, 2); ak += __shfl_xor(ak, 4);
  av += __shfl_xor(av, 1); av += __shfl_xor(av, 2); av += __shfl_xor(av, 4);
  if (sub == 0){
    kb[(b * 4 + s) * DD + hd] = ak + bk[hd];
    vb[(b * 4 + s) * DD + hd] = av + bv[hd];
  }
}

__global__ void prep_mu(const float* __restrict__ kb, const float* __restrict__ vb,
                        const float* __restrict__ Wq, const float* __restrict__ bq,
                        const float* __restrict__ Wo, const float* __restrict__ bo,
                        const float* __restrict__ Wg1,
                        const float* __restrict__ glng, const float* __restrict__ glnb,
                        const float* __restrict__ bg1,
                        unsigned short* __restrict__ mB, unsigned short* __restrict__ uT,
                        float* __restrict__ cArr, unsigned short* __restrict__ wg1B,
                        float* __restrict__ e1, float* __restrict__ e2){
  int idx = blockIdx.x * 256 + threadIdx.x;     // 328064 total
  if (idx < 131072){
    int d = idx & 511; int j = (idx >> 9) & 31; int b = idx >> 14;
    int h = j >> 2, s = j & 3;
    const float* kr = kb + (b * 4 + s) * DD + h * 64;
    const float* wq = Wq + (size_t)(h * 64) * DD + d;
    float acc = 0.f;
#pragma unroll 16
    for (int dh = 0; dh < 64; dh++) acc += wq[(size_t)dh * DD] * kr[dh];
    mB[idx] = f2bf(acc);
  } else if (idx < 262144){
    int t = idx - 131072;
    int j = t & 31; int d = (t >> 5) & 511; int b = t >> 14;
    int h = j >> 2, s = j & 3;
    const float* vr = vb + (b * 4 + s) * DD + h * 64;
    const float* wo = Wo + (size_t)d * DD + h * 64;
    float acc = 0.f;
#pragma unroll 8
    for (int dh = 0; dh < 64; dh += 4){
      float4 v4 = *(const float4*)(vr + dh);
      float4 w4 = *(const float4*)(wo + dh);
      acc += v4.x * w4.x + v4.y * w4.y + v4.z * w4.z + v4.w * w4.w;
    }
    // fold bo: sum_j w[t][j] == 8 exactly, so adding bo[d]/8 to every u column
    // makes W·u' == att + bo with zero cost in the main kernel.
    uT[b * 16384 + d * 32 + j] = f2bf(acc + bo[d] * 0.125f);
  } else if (idx < 327680){
    int t = idx - 262144;
    wg1B[t] = f2bf(Wg1[t] * glng[t & 511]);
  } else if (idx < 327936){
    int t = idx - 327680; int j = t & 31, b = t >> 5;
    int h = j >> 2, s = j & 3;
    const float* kr = kb + (b * 4 + s) * DD + h * 64;
    const float* bqp = bq + h * 64;
    float acc = 0.f;
    for (int dh = 0; dh < 64; dh++) acc += bqp[dh] * kr[dh];
    cArr[b * 32 + j] = acc;
  } else if (idx < 328064){
    int col = idx - 327936;
    const float* wr = Wg1 + (size_t)col * DD;
    float a1 = 0.f, a2 = 0.f;
    for (int d = 0; d < DD; d += 4){
      float4 w  = *(const float4*)(wr + d);
      float4 gm = *(const float4*)(glng + d);
      float4 bt = *(const float4*)(glnb + d);
      a1 += w.x * gm.x + w.y * gm.y + w.z * gm.z + w.w * gm.w;
      a2 += w.x * bt.x + w.y * bt.y + w.z * bt.z + w.w * bt.w;
    }
    e1[col] = a1; e2[col] = a2 + bg1[col];
  }
}

// ---------------- main fused kernel: 1 wave, 16 tokens, pipelined ----------------

__global__ __launch_bounds__(64) void fused_main(
    const float* __restrict__ xin,
    const float* __restrict__ e1v, const float* __restrict__ e2v,
    const float* __restrict__ wg2v, const float* __restrict__ bg2v,
    const float* __restrict__ lng, const float* __restrict__ lnb,
    const unsigned short* __restrict__ mB,
    const unsigned short* __restrict__ uTB,
    const float* __restrict__ cArr,
    const unsigned short* __restrict__ wg1B,
    float* __restrict__ outF, float* __restrict__ outAW, float* __restrict__ outG)
{
  __shared__ __align__(16) unsigned short Yb[TT * DD];   // 16 KB: x bf16, then y bf16
  __shared__ __align__(16) unsigned short Wl[TT * 32];   // 1 KB softmax weights

  const int lane = threadIdx.x;
  const int r16 = lane & 15;
  const int kg  = lane >> 4;
  const int bb  = blockIdx.x >> 8;
  const int t0  = (blockIdx.x & 255) << 4;
  const size_t rowbase = (size_t)bb * TN + t0;
  const int swzS = (r16 & 7) << 3;   // short-index XOR swizzle for row r16

  const float c0v  = cArr[bb * 32 + r16];
  const float c1v  = cArr[bb * 32 + r16 + 16];
  const float bg2s = bg2v[0];

  const float* xr = xin + (rowbase + r16) * DD + kg * 8;
  const unsigned short* mb0 = mB + (size_t)bb * 32 * DD + r16 * DD + kg * 8;
  const unsigned short* mb1 = mb0 + 16 * DD;
  const unsigned short* wgp = wg1B + (size_t)r16 * DD + kg * 8;

  // ---- pipeline prologue: x depth-2, frags depth-1 ----
  float4 xa0 = *(const float4*)(xr);
  float4 xa1 = *(const float4*)(xr + 4);
  float4 xb0 = *(const float4*)(xr + 32);
  float4 xb1 = *(const float4*)(xr + 36);
  short8 b0n = *(const short8*)(mb0);
  short8 b1n = *(const short8*)(mb1);
  short8 wfn[8];
#pragma unroll
  for (int nt = 0; nt < 8; nt++) wfn[nt] = *(const short8*)(wgp + (size_t)nt * 16 * DD);

  f32x4 sa0 = {0.f,0.f,0.f,0.f}, sa1 = {0.f,0.f,0.f,0.f};
  f32x4 gacc[8];
#pragma unroll
  for (int nt = 0; nt < 8; nt++){ f32x4 z = {0.f,0.f,0.f,0.f}; gacc[nt] = z; }
  float s = 0.f, q = 0.f;

  // ---- merged phase 0+1: per kt: prefetch kt+1 frags / kt+2 x; MFMA kt ----
#pragma unroll
  for (int kt = 0; kt < 16; kt++){
    float4 x0 = xa0, x1 = xa1;
    xa0 = xb0; xa1 = xb1;
    short8 b0 = b0n, b1 = b1n;
    short8 wf[8];
#pragma unroll
    for (int nt = 0; nt < 8; nt++) wf[nt] = wfn[nt];
    if (kt < 14){
      xb0 = *(const float4*)(xr + (kt + 2) * 32);
      xb1 = *(const float4*)(xr + (kt + 2) * 32 + 4);
    }
    if (kt < 15){
      b0n = *(const short8*)(mb0 + (kt + 1) * 32);
      b1n = *(const short8*)(mb1 + (kt + 1) * 32);
#pragma unroll
      for (int nt = 0; nt < 8; nt++)
        wfn[nt] = *(const short8*)(wgp + (size_t)nt * 16 * DD + (kt + 1) * 32);
    }
    float xv[8] = {x0.x, x0.y, x0.z, x0.w, x1.x, x1.y, x1.z, x1.w};
    short8 a;
#pragma unroll
    for (int j = 0; j < 8; j++){
      s += xv[j]; q += xv[j] * xv[j];
      a[j] = (short)f2bf(xv[j]);
    }
    *(short8*)&Yb[r16 * DD + ((kt * 32 + kg * 8) ^ swzS)] = a;
    sa0 = __builtin_amdgcn_mfma_f32_16x16x32_bf16(a, b0, sa0, 0, 0, 0);
    sa1 = __builtin_amdgcn_mfma_f32_16x16x32_bf16(a, b1, sa1, 0, 0, 0);
#pragma unroll
    for (int nt = 0; nt < 8; nt++)
      gacc[nt] = __builtin_amdgcn_mfma_f32_16x16x32_bf16(wf[nt], a, gacc[nt], 0, 0, 0);
  }

  // ---- early-issue phase-3/4 loads (consumed much later; fully hidden) ----
  const unsigned short* ub = uTB + (size_t)bb * DD * 32 + r16 * 32 + kg * 8;
  short8 ufn[8];
#pragma unroll
  for (int nt = 0; nt < 8; nt++) ufn[nt] = *(const short8*)(ub + (size_t)(nt * 16) * 32);
  const int c0 = lane << 3;
  float4 lgA0 = *(const float4*)(lng + c0);
  float4 lgA1 = *(const float4*)(lng + c0 + 4);
  float4 lbA0 = *(const float4*)(lnb + c0);
  float4 lbA1 = *(const float4*)(lnb + c0 + 4);

  // ---- LN stats (gate-LN, fp32 exact) ----
  s += __shfl_xor(s, 16); s += __shfl_xor(s, 32);
  q += __shfl_xor(q, 16); q += __shfl_xor(q, 32);
  const float mu = s * (1.f / DD);
  const float rs = rsqrtf(q * (1.f / DD) - mu * mu + 1e-5f);

  // ---- softmax epilogue: thread owns tokens kg*4+r at head-idx j = r16 ----
#pragma unroll
  for (int r = 0; r < 4; r++){
    float s0 = (sa0[r] + c0v) * 0.125f;
    float s1 = (sa1[r] + c1v) * 0.125f;
    float mx0 = fmaxf(s0, __shfl_xor(s0, 1)); mx0 = fmaxf(mx0, __shfl_xor(mx0, 2));
    float mx1 = fmaxf(s1, __shfl_xor(s1, 1)); mx1 = fmaxf(mx1, __shfl_xor(mx1, 2));
    float e0 = __expf(s0 - mx0), e1x = __expf(s1 - mx1);
    float d0 = e0;  d0 += __shfl_xor(d0, 1); d0 += __shfl_xor(d0, 2);
    float d1 = e1x; d1 += __shfl_xor(d1, 1); d1 += __shfl_xor(d1, 2);
    float w0 = e0 / d0, w1 = e1x / d1;
    float t = w0 + w1; t += __shfl_xor(t, 4); t += __shfl_xor(t, 8); t *= 0.125f;
    const int rw = kg * 4 + r;
    if ((lane & 12) == 0) outAW[(rowbase + rw) * 4 + (lane & 3)] = t;
    Wl[rw * 32 + r16]      = f2bf(w0);
    Wl[rw * 32 + r16 + 16] = f2bf(w1);
  }

  // ---- gate epilogue: thread owns token r16 ----
  float g_reg;
  {
    float part = 0.f;
#pragma unroll
    for (int nt = 0; nt < 8; nt++){
      const int c4 = nt * 16 + kg * 4;
      float4 e1c = *(const float4*)(e1v + c4);
      float4 e2c = *(const float4*)(e2v + c4);
      float4 w2c = *(const float4*)(wg2v + c4);
      float e1a[4] = {e1c.x, e1c.y, e1c.z, e1c.w};
      float e2a[4] = {e2c.x, e2c.y, e2c.z, e2c.w};
      float w2a[4] = {w2c.x, w2c.y, w2c.z, w2c.w};
#pragma unroll
      for (int r = 0; r < 4; r++){
        float gv = rs * (gacc[nt][r] - mu * e1a[r]) + e2a[r];
        gv = fmaxf(gv, 0.f);
        part += gv * w2a[r];
      }
    }
    part += __shfl_xor(part, 16); part += __shfl_xor(part, 32);
    g_reg = 1.f / (1.f + __expf(-(part + bg2s)));
    if (kg == 0) outG[rowbase + r16] = g_reg;
  }

  // ---- phase 3: ATT + residual (x from Yb), y back into Yb; pipelined over nc ----
  short8 aw = *(const short8*)&Wl[r16 * 32 + kg * 8];
  float psum = 0.f, psq = 0.f;
#pragma unroll
  for (int nc = 0; nc < 4; nc++){
    short8 uf[8];
#pragma unroll
    for (int nt = 0; nt < 8; nt++) uf[nt] = ufn[nt];
    if (nc < 3){
#pragma unroll
      for (int nt = 0; nt < 8; nt++)
        ufn[nt] = *(const short8*)(ub + (size_t)((nc + 1) * 128 + nt * 16) * 32);
    }
    uint2v xch[8];
#pragma unroll
    for (int nt = 0; nt < 8; nt++)
      xch[nt] = *(const uint2v*)&Yb[r16 * DD + ((nc * 128 + nt * 16 + kg * 4) ^ swzS)];
    f32x4 acc[8];
#pragma unroll
    for (int nt = 0; nt < 8; nt++){
      f32x4 z = {0.f,0.f,0.f,0.f};
      acc[nt] = __builtin_amdgcn_mfma_f32_16x16x32_bf16(uf[nt], aw, z, 0, 0, 0);
    }
#pragma unroll
    for (int nt = 0; nt < 8; nt++){
      unsigned int lo = xch[nt][0], hi = xch[nt][1];
      float y0 = bf2f((unsigned short)(lo & 0xffffu)) + g_reg * acc[nt][0];
      float y1 = bf2f((unsigned short)(lo >> 16))     + g_reg * acc[nt][1];
      float y2 = bf2f((unsigned short)(hi & 0xffffu)) + g_reg * acc[nt][2];
      float y3 = bf2f((unsigned short)(hi >> 16))     + g_reg * acc[nt][3];
      psum += (y0 + y1) + (y2 + y3);
      psq  += (y0 * y0 + y1 * y1) + (y2 * y2 + y3 * y3);
      uint2v yp;
      yp[0] = (unsigned)f2bf(y0) | ((unsigned)f2bf(y1) << 16);
      yp[1] = (unsigned)f2bf(y2) | ((unsigned)f2bf(y3) << 16);
      *(uint2v*)&Yb[r16 * DD + ((nc * 128 + nt * 16 + kg * 4) ^ swzS)] = yp;
    }
  }

  // ---- final-LN stats ----
  psum += __shfl_xor(psum, 16); psum += __shfl_xor(psum, 32);
  psq  += __shfl_xor(psq, 16);  psq  += __shfl_xor(psq, 32);
  const float mu2 = psum * (1.f / DD);
  const float rs2 = rsqrtf(psq * (1.f / DD) - mu2 * mu2 + 1e-5f);

  // ---- phase 4: final LN + contiguous fp32 row stores ----
  float lg[8]  = {lgA0.x, lgA0.y, lgA0.z, lgA0.w, lgA1.x, lgA1.y, lgA1.z, lgA1.w};
  float lb8[8] = {lbA0.x, lbA0.y, lbA0.z, lbA0.w, lbA1.x, lbA1.y, lbA1.z, lbA1.w};
#pragma unroll
  for (int r = 0; r < TT; r++){
    const float m2  = __shfl(mu2, r);
    const float r2v = __shfl(rs2, r);
    short8 yv = *(const short8*)&Yb[r * DD + (c0 ^ ((r & 7) << 3))];
    float o[8];
#pragma unroll
    for (int j = 0; j < 8; j++)
      o[j] = (bf2f((unsigned short)yv[j]) - m2) * r2v * lg[j] + lb8[j];
    float* op = outF + (rowbase + r) * DD + c0;
    float4 o0; o0.x = o[0]; o0.y = o[1]; o0.z = o[2]; o0.w = o[3];
    float4 o1; o1.x = o[4]; o1.y = o[5]; o1.z = o[6]; o1.w = o[7];
    *(float4*)op = o0;
    *(float4*)(op + 4) = o1;
  }
}

// ---------------- launch ----------------

extern "C" void kernel_launch(void* const* d_in, const int* in_sizes, int n_in,
                              void* d_out, int out_size, void* d_ws, size_t ws_size,
                              hipStream_t stream)
{
  const float* token = (const float*)d_in[0];
  const float* semb  = (const float*)d_in[1];
  const float* We    = (const float*)d_in[2];
  const float* be    = (const float*)d_in[3];
  const float* spos  = (const float*)d_in[4];
  const float* Wq    = (const float*)d_in[5];
  const float* bq    = (const float*)d_in[6];
  const float* Wk    = (const float*)d_in[7];
  const float* bk    = (const float*)d_in[8];
  const float* Wv    = (const float*)d_in[9];
  const float* bv    = (const float*)d_in[10];
  const float* Wo    = (const float*)d_in[11];
  const float* bo    = (const float*)d_in[12];
  const float* glng  = (const float*)d_in[13];
  const float* glnb  = (const float*)d_in[14];
  const float* Wg1   = (const float*)d_in[15];
  const float* bg1   = (const float*)d_in[16];
  const float* Wg2   = (const float*)d_in[17];
  const float* bg2   = (const float*)d_in[18];
  const float* lng   = (const float*)d_in[19];
  const float* lnb   = (const float*)d_in[20];

  char* ws = (char*)d_ws;
  float* e1             = (float*)(ws + 0);        // 512 B (spk region reused)
  float* e2             = (float*)(ws + 512);
  float* spk            = (float*)(ws + 0);        // 64 KB (dead before e1/e2 written)
  float* kb             = (float*)(ws + 65536);
  float* vb             = (float*)(ws + 131072);
  unsigned short* mB    = (unsigned short*)(ws + 196608);
  unsigned short* uTB   = (unsigned short*)(ws + 458752);
  float* cArr           = (float*)(ws + 720896);
  unsigned short* wg1B  = (unsigned short*)(ws + 721920);

  float* outF  = (float*)d_out;
  float* outAW = outF + (size_t)NB * TN * DD;
  float* outG  = outAW + (size_t)NB * TN * 4;

  prep_spk<<<dim3(512), dim3(256), 0, stream>>>(semb, We, be, spos, spk);
  prep_kv<<<dim3(512), dim3(256), 0, stream>>>(spk, Wk, bk, Wv, bv, kb, vb);
  prep_mu<<<dim3(1282), dim3(256), 0, stream>>>(kb, vb, Wq, bq, Wo, bo, Wg1, glng, glnb, bg1,
                                                mB, uTB, cArr, wg1B, e1, e2);
  fused_main<<<dim3(NB * TN / TT), dim3(64), 0, stream>>>(
      token, e1, e2, Wg2, bg2, lng, lnb,
      mB, uTB, cArr, wg1B, outF, outAW, outG);
}

// Round 5
// 95.941 us; speedup vs baseline: 1.2695x; 1.0131x over previous
//
#include <hip/hip_runtime.h>
#include <hip/hip_bf16.h>
#include <stdint.h>

typedef __attribute__((ext_vector_type(8))) short short8;
typedef __attribute__((ext_vector_type(4))) float f32x4;
typedef __attribute__((ext_vector_type(2))) unsigned int uint2v;

#define DD 512
#define TT 16   // tokens per block (1 wave)
#define TN 4096 // T
#define NB 8    // B

__device__ __forceinline__ unsigned short f2bf(float f){
  uint32_t u = __float_as_uint(f);
  u += 0x7FFFu + ((u >> 16) & 1u);
  return (unsigned short)(u >> 16);
}
__device__ __forceinline__ float bf2f(unsigned short h){
  return __uint_as_float(((uint32_t)h) << 16);
}

// ---------------- prep kernels (16-way-split dots) ----------------

__global__ void prep_spk(const float* __restrict__ se, const float* __restrict__ We,
                         const float* __restrict__ be, const float* __restrict__ spos,
                         float* __restrict__ spk){
  int idx = blockIdx.x * 256 + threadIdx.x;   // 262144
  int sub = idx & 15; int out = idx >> 4;
  int b = out & 7, od = out >> 3;
  const float* wr = We + (size_t)od * DD + sub * 4;
  const float* sb = se + b * DD + sub * 4;
  float acc = 0.f;
#pragma unroll
  for (int i = 0; i < 8; i++){
    float4 w = *(const float4*)(wr + i * 64);
    float4 x = *(const float4*)(sb + i * 64);
    acc += w.x * x.x + w.y * x.y + w.z * x.z + w.w * x.w;
  }
  acc += __shfl_xor(acc, 1); acc += __shfl_xor(acc, 2);
  acc += __shfl_xor(acc, 4); acc += __shfl_xor(acc, 8);
  if (sub == 0) spk[b * 2048 + od] = fmaxf(acc + be[od], 0.f) + spos[od];
}

__global__ void prep_kv(const float* __restrict__ spk, const float* __restrict__ Wk,
                        const float* __restrict__ bk, const float* __restrict__ Wv,
                        const float* __restrict__ bv, float* __restrict__ kb,
                        float* __restrict__ vb){
  int idx = blockIdx.x * 256 + threadIdx.x;   // 262144
  int sub = idx & 15; int out = idx >> 4;
  int hd = out >> 5; int r = out & 31; int b = r >> 2, s = r & 3;
  const float* sp  = spk + (b * 4 + s) * DD + sub * 4;
  const float* wkr = Wk + (size_t)hd * DD + sub * 4;
  const float* wvr = Wv + (size_t)hd * DD + sub * 4;
  float ak = 0.f, av = 0.f;
#pragma unroll
  for (int i = 0; i < 8; i++){
    float4 x  = *(const float4*)(sp + i * 64);
    float4 wk = *(const float4*)(wkr + i * 64);
    float4 wv = *(const float4*)(wvr + i * 64);
    ak += x.x * wk.x + x.y * wk.y + x.z * wk.z + x.w * wk.w;
    av += x.x * wv.x + x.y * wv.y + x.z * wv.z + x.w * wv.w;
  }
  ak += __shfl_xor(ak, 1); ak += __shfl_xor(ak, 2);
  ak += __shfl_xor(ak, 4); ak += __shfl_xor(ak, 8);
  av += __shfl_xor(av, 1); av += __shfl_xor(av, 2);
  av += __shfl_xor(av, 4); av += __shfl_xor(av, 8);
  if (sub == 0){
    kb[(b * 4 + s) * DD + hd] = ak + bk[hd];
    vb[(b * 4 + s) * DD + hd] = av + bv[hd];
  }
}

__global__ void prep_mu(const float* __restrict__ kb, const float* __restrict__ vb,
                        const float* __restrict__ Wq, const float* __restrict__ bq,
                        const float* __restrict__ Wo, const float* __restrict__ bo,
                        const float* __restrict__ Wg1,
                        const float* __restrict__ glng, const float* __restrict__ glnb,
                        const float* __restrict__ bg1,
                        unsigned short* __restrict__ mB, unsigned short* __restrict__ uT,
                        float* __restrict__ cArr, unsigned short* __restrict__ wg1B,
                        float* __restrict__ e1, float* __restrict__ e2){
  int idx = blockIdx.x * 256 + threadIdx.x;     // 328064 total
  if (idx < 131072){
    int d = idx & 511; int j = (idx >> 9) & 31; int b = idx >> 14;
    int h = j >> 2, s = j & 3;
    const float* kr = kb + (b * 4 + s) * DD + h * 64;
    const float* wq = Wq + (size_t)(h * 64) * DD + d;
    float acc = 0.f;
#pragma unroll 16
    for (int dh = 0; dh < 64; dh++) acc += wq[(size_t)dh * DD] * kr[dh];
    mB[idx] = f2bf(acc);
  } else if (idx < 262144){
    int t = idx - 131072;
    int j = t & 31; int d = (t >> 5) & 511; int b = t >> 14;
    int h = j >> 2, s = j & 3;
    const float* vr = vb + (b * 4 + s) * DD + h * 64;
    const float* wo = Wo + (size_t)d * DD + h * 64;
    float acc = 0.f;
#pragma unroll 8
    for (int dh = 0; dh < 64; dh += 4){
      float4 v4 = *(const float4*)(vr + dh);
      float4 w4 = *(const float4*)(wo + dh);
      acc += v4.x * w4.x + v4.y * w4.y + v4.z * w4.z + v4.w * w4.w;
    }
    // fold bo: sum_j w[t][j] == 8 exactly (softmax over 4 per head, 8 heads at
    // weight 1 each... actually sum over the 32 j-slots = 8), so bo[d]/8 per
    // column makes W·u' == att + bo for free.
    uT[b * 16384 + d * 32 + j] = f2bf(acc + bo[d] * 0.125f);
  } else if (idx < 327680){
    int t = idx - 262144;
    wg1B[t] = f2bf(Wg1[t] * glng[t & 511]);
  } else if (idx < 327936){
    int t = idx - 327680; int j = t & 31, b = t >> 5;
    int h = j >> 2, s = j & 3;
    const float* kr = kb + (b * 4 + s) * DD + h * 64;
    const float* bqp = bq + h * 64;
    float acc = 0.f;
    for (int dh = 0; dh < 64; dh++) acc += bqp[dh] * kr[dh];
    cArr[b * 32 + j] = acc;
  } else if (idx < 328064){
    int col = idx - 327936;
    const float* wr = Wg1 + (size_t)col * DD;
    float a1 = 0.f, a2 = 0.f;
    for (int d = 0; d < DD; d += 4){
      float4 w  = *(const float4*)(wr + d);
      float4 gm = *(const float4*)(glng + d);
      float4 bt = *(const float4*)(glnb + d);
      a1 += w.x * gm.x + w.y * gm.y + w.z * gm.z + w.w * gm.w;
      a2 += w.x * bt.x + w.y * bt.y + w.z * bt.z + w.w * bt.w;
    }
    e1[col] = a1; e2[col] = a2 + bg1[col];
  }
}

// ---------------- main fused kernel: 1 wave, 16 tokens ----------------

__global__ __launch_bounds__(64) void fused_main(
    const float* __restrict__ xin,
    const float* __restrict__ e1v, const float* __restrict__ e2v,
    const float* __restrict__ wg2v, const float* __restrict__ bg2v,
    const float* __restrict__ lng, const float* __restrict__ lnb,
    const unsigned short* __restrict__ mB,
    const unsigned short* __restrict__ uTB,
    const float* __restrict__ cArr,
    const unsigned short* __restrict__ wg1B,
    float* __restrict__ outF, float* __restrict__ outAW, float* __restrict__ outG)
{
  __shared__ __align__(16) unsigned short Yb[TT * DD];   // 16 KB: x bf16, then y bf16
  __shared__ __align__(16) unsigned short Wl[TT * 32];   // 1 KB softmax weights

  const int lane = threadIdx.x;
  const int r16 = lane & 15;
  const int kg  = lane >> 4;
  const int bb  = blockIdx.x >> 8;
  const int t0  = (blockIdx.x & 255) << 4;
  const size_t rowbase = (size_t)bb * TN + t0;
  const int swzS = (r16 & 7) << 3;   // short-index XOR swizzle for row r16

  // ---- Phase 0: issue ALL x loads (32 KB/wave outstanding), then convert ----
  const float* xr = xin + (rowbase + r16) * DD + kg * 8;
  float4 xl[32];
#pragma unroll
  for (int i = 0; i < 32; i++)
    xl[i] = *(const float4*)(xr + (i >> 1) * 32 + (i & 1) * 4);

  short8 af[16];
  float s = 0.f, q = 0.f;
#pragma unroll
  for (int kt = 0; kt < 16; kt++){
    float xv[8] = {xl[2*kt].x, xl[2*kt].y, xl[2*kt].z, xl[2*kt].w,
                   xl[2*kt+1].x, xl[2*kt+1].y, xl[2*kt+1].z, xl[2*kt+1].w};
    short8 pk;
#pragma unroll
    for (int j = 0; j < 8; j++){
      s += xv[j]; q += xv[j] * xv[j];
      pk[j] = (short)f2bf(xv[j]);
    }
    af[kt] = pk;
    *(short8*)&Yb[r16 * DD + ((kt * 32 + kg * 8) ^ swzS)] = pk;
  }
  s += __shfl_xor(s, 16); s += __shfl_xor(s, 32);
  q += __shfl_xor(q, 16); q += __shfl_xor(q, 32);
  const float mu = s * (1.f / DD);
  const float rs = rsqrtf(q * (1.f / DD) - mu * mu + 1e-5f);

  // ---- Phase 1: scores + gate GEMM off register A-frags (plain loads) ----
  const unsigned short* mb0 = mB + (size_t)bb * 32 * DD + r16 * DD + kg * 8;
  const unsigned short* mb1 = mb0 + 16 * DD;
  const unsigned short* wgp = wg1B + (size_t)r16 * DD + kg * 8;

  f32x4 sa0 = {0.f,0.f,0.f,0.f}, sa1 = {0.f,0.f,0.f,0.f};
  f32x4 gacc[8];
#pragma unroll
  for (int nt = 0; nt < 8; nt++){ f32x4 z = {0.f,0.f,0.f,0.f}; gacc[nt] = z; }
#pragma unroll
  for (int kt = 0; kt < 16; kt++){
    const int kc = kt * 32;
    short8 b0 = *(const short8*)(mb0 + kc);
    short8 b1 = *(const short8*)(mb1 + kc);
    sa0 = __builtin_amdgcn_mfma_f32_16x16x32_bf16(af[kt], b0, sa0, 0, 0, 0);
    sa1 = __builtin_amdgcn_mfma_f32_16x16x32_bf16(af[kt], b1, sa1, 0, 0, 0);
#pragma unroll
    for (int nt = 0; nt < 8; nt++){
      short8 wf = *(const short8*)(wgp + (size_t)nt * 16 * DD + kc);
      gacc[nt] = __builtin_amdgcn_mfma_f32_16x16x32_bf16(wf, af[kt], gacc[nt], 0, 0, 0);
    }
  }

  // ---- issue gate-epilogue operand loads early (hidden under softmax) ----
  float4 e1c[8], e2c[8], w2c[8];
#pragma unroll
  for (int nt = 0; nt < 8; nt++){
    const int c4 = nt * 16 + kg * 4;
    e1c[nt] = *(const float4*)(e1v + c4);
    e2c[nt] = *(const float4*)(e2v + c4);
    w2c[nt] = *(const float4*)(wg2v + c4);
  }
  const float c0v  = cArr[bb * 32 + r16];
  const float c1v  = cArr[bb * 32 + r16 + 16];
  const float bg2s = bg2v[0];

  // ---- softmax epilogue: thread owns tokens kg*4+r at head-idx j = r16 ----
#pragma unroll
  for (int r = 0; r < 4; r++){
    float s0 = (sa0[r] + c0v) * 0.125f;
    float s1 = (sa1[r] + c1v) * 0.125f;
    float mx0 = fmaxf(s0, __shfl_xor(s0, 1)); mx0 = fmaxf(mx0, __shfl_xor(mx0, 2));
    float mx1 = fmaxf(s1, __shfl_xor(s1, 1)); mx1 = fmaxf(mx1, __shfl_xor(mx1, 2));
    float e0 = __expf(s0 - mx0), e1x = __expf(s1 - mx1);
    float d0 = e0;  d0 += __shfl_xor(d0, 1); d0 += __shfl_xor(d0, 2);
    float d1 = e1x; d1 += __shfl_xor(d1, 1); d1 += __shfl_xor(d1, 2);
    float w0 = e0 / d0, w1 = e1x / d1;
    float t = w0 + w1; t += __shfl_xor(t, 4); t += __shfl_xor(t, 8); t *= 0.125f;
    const int rw = kg * 4 + r;
    if ((lane & 12) == 0) outAW[(rowbase + rw) * 4 + (lane & 3)] = t;
    Wl[rw * 32 + r16]      = f2bf(w0);
    Wl[rw * 32 + r16 + 16] = f2bf(w1);
  }

  // ---- read attention-weight fragment + issue LN weight loads early ----
  short8 aw = *(const short8*)&Wl[r16 * 32 + kg * 8];
  const unsigned short* ub = uTB + (size_t)bb * DD * 32 + r16 * 32 + kg * 8;
  const int c0 = lane << 3;
  float4 lgA0 = *(const float4*)(lng + c0);
  float4 lgA1 = *(const float4*)(lng + c0 + 4);
  float4 lbA0 = *(const float4*)(lnb + c0);
  float4 lbA1 = *(const float4*)(lnb + c0 + 4);

  // ---- gate epilogue: thread owns token r16 ----
  float g_reg;
  {
    float part = 0.f;
#pragma unroll
    for (int nt = 0; nt < 8; nt++){
      float e1a[4] = {e1c[nt].x, e1c[nt].y, e1c[nt].z, e1c[nt].w};
      float e2a[4] = {e2c[nt].x, e2c[nt].y, e2c[nt].z, e2c[nt].w};
      float w2a[4] = {w2c[nt].x, w2c[nt].y, w2c[nt].z, w2c[nt].w};
#pragma unroll
      for (int r = 0; r < 4; r++){
        float gv = rs * (gacc[nt][r] - mu * e1a[r]) + e2a[r];
        gv = fmaxf(gv, 0.f);
        part += gv * w2a[r];
      }
    }
    part += __shfl_xor(part, 16); part += __shfl_xor(part, 32);
    g_reg = 1.f / (1.f + __expf(-(part + bg2s)));
    if (kg == 0) outG[rowbase + r16] = g_reg;
  }

  // ---- phase 3: ATT + residual (x from Yb), y back into Yb ----
  float psum = 0.f, psq = 0.f;
#pragma unroll
  for (int nc = 0; nc < 4; nc++){
    f32x4 acc[8];
#pragma unroll
    for (int nt = 0; nt < 8; nt++){
      short8 uf = *(const short8*)(ub + (size_t)(nc * 128 + nt * 16) * 32);
      f32x4 z = {0.f,0.f,0.f,0.f};
      acc[nt] = __builtin_amdgcn_mfma_f32_16x16x32_bf16(uf, aw, z, 0, 0, 0);
    }
#pragma unroll
    for (int nt = 0; nt < 8; nt++){
      const int idx = r16 * DD + ((nc * 128 + nt * 16 + kg * 4) ^ swzS);
      uint2v xch = *(const uint2v*)&Yb[idx];
      unsigned int lo = xch[0], hi = xch[1];
      float y0 = bf2f((unsigned short)(lo & 0xffffu)) + g_reg * acc[nt][0];
      float y1 = bf2f((unsigned short)(lo >> 16))     + g_reg * acc[nt][1];
      float y2 = bf2f((unsigned short)(hi & 0xffffu)) + g_reg * acc[nt][2];
      float y3 = bf2f((unsigned short)(hi >> 16))     + g_reg * acc[nt][3];
      psum += (y0 + y1) + (y2 + y3);
      psq  += (y0 * y0 + y1 * y1) + (y2 * y2 + y3 * y3);
      uint2v yp;
      yp[0] = (unsigned)f2bf(y0) | ((unsigned)f2bf(y1) << 16);
      yp[1] = (unsigned)f2bf(y2) | ((unsigned)f2bf(y3) << 16);
      *(uint2v*)&Yb[idx] = yp;
    }
  }

  // ---- final-LN stats ----
  psum += __shfl_xor(psum, 16); psum += __shfl_xor(psum, 32);
  psq  += __shfl_xor(psq, 16);  psq  += __shfl_xor(psq, 32);
  const float mu2 = psum * (1.f / DD);
  const float rs2 = rsqrtf(psq * (1.f / DD) - mu2 * mu2 + 1e-5f);

  // ---- phase 4: final LN + contiguous fp32 row stores ----
  float lg[8]  = {lgA0.x, lgA0.y, lgA0.z, lgA0.w, lgA1.x, lgA1.y, lgA1.z, lgA1.w};
  float lb8[8] = {lbA0.x, lbA0.y, lbA0.z, lbA0.w, lbA1.x, lbA1.y, lbA1.z, lbA1.w};
#pragma unroll
  for (int r = 0; r < TT; r++){
    const float m2  = __shfl(mu2, r);
    const float r2v = __shfl(rs2, r);
    short8 yv = *(const short8*)&Yb[r * DD + (c0 ^ ((r & 7) << 3))];
    float o[8];
#pragma unroll
    for (int j = 0; j < 8; j++)
      o[j] = (bf2f((unsigned short)yv[j]) - m2) * r2v * lg[j] + lb8[j];
    float* op = outF + (rowbase + r) * DD + c0;
    float4 o0; o0.x = o[0]; o0.y = o[1]; o0.z = o[2]; o0.w = o[3];
    float4 o1; o1.x = o[4]; o1.y = o[5]; o1.z = o[6]; o1.w = o[7];
    *(float4*)op = o0;
    *(float4*)(op + 4) = o1;
  }
}

// ---------------- launch ----------------

extern "C" void kernel_launch(void* const* d_in, const int* in_sizes, int n_in,
                              void* d_out, int out_size, void* d_ws, size_t ws_size,
                              hipStream_t stream)
{
  const float* token = (const float*)d_in[0];
  const float* semb  = (const float*)d_in[1];
  const float* We    = (const float*)d_in[2];
  const float* be    = (const float*)d_in[3];
  const float* spos  = (const float*)d_in[4];
  const float* Wq    = (const float*)d_in[5];
  const float* bq    = (const float*)d_in[6];
  const float* Wk    = (const float*)d_in[7];
  const float* bk    = (const float*)d_in[8];
  const float* Wv    = (const float*)d_in[9];
  const float* bv    = (const float*)d_in[10];
  const float* Wo    = (const float*)d_in[11];
  const float* bo    = (const float*)d_in[12];
  const float* glng  = (const float*)d_in[13];
  const float* glnb  = (const float*)d_in[14];
  const float* Wg1   = (const float*)d_in[15];
  const float* bg1   = (const float*)d_in[16];
  const float* Wg2   = (const float*)d_in[17];
  const float* bg2   = (const float*)d_in[18];
  const float* lng   = (const float*)d_in[19];
  const float* lnb   = (const float*)d_in[20];

  char* ws = (char*)d_ws;
  float* e1             = (float*)(ws + 0);        // 512 B (spk region reused)
  float* e2             = (float*)(ws + 512);
  float* spk            = (float*)(ws + 0);        // 64 KB (dead before e1/e2 written)
  float* kb             = (float*)(ws + 65536);
  float* vb             = (float*)(ws + 131072);
  unsigned short* mB    = (unsigned short*)(ws + 196608);
  unsigned short* uTB   = (unsigned short*)(ws + 458752);
  float* cArr           = (float*)(ws + 720896);
  unsigned short* wg1B  = (unsigned short*)(ws + 721920);

  float* outF  = (float*)d_out;
  float* outAW = outF + (size_t)NB * TN * DD;
  float* outG  = outAW + (size_t)NB * TN * 4;

  prep_spk<<<dim3(1024), dim3(256), 0, stream>>>(semb, We, be, spos, spk);
  prep_kv<<<dim3(1024), dim3(256), 0, stream>>>(spk, Wk, bk, Wv, bv, kb, vb);
  prep_mu<<<dim3(1282), dim3(256), 0, stream>>>(kb, vb, Wq, bq, Wo, bo, Wg1, glng, glnb, bg1,
                                                mB, uTB, cArr, wg1B, e1, e2);
  fused_main<<<dim3(NB * TN / TT), dim3(64), 0, stream>>>(
      token, e1, e2, Wg2, bg2, lng, lnb,
      mB, uTB, cArr, wg1B, outF, outAW, outG);
}

// Round 6
// 71.580 us; speedup vs baseline: 1.7016x; 1.3403x over previous
//
#include <hip/hip_runtime.h>
#include <hip/hip_bf16.h>
#include <stdint.h>

typedef __attribute__((ext_vector_type(8))) short short8;
typedef __attribute__((ext_vector_type(4))) short short4v;
typedef __attribute__((ext_vector_type(4))) float f32x4;
typedef __attribute__((ext_vector_type(2))) unsigned int uint2v;

#define DD 512
#define TT 16   // tokens per block (1 wave)
#define TN 4096 // T
#define NB 8    // B

__device__ __forceinline__ unsigned short f2bf(float f){
  uint32_t u = __float_as_uint(f);
  u += 0x7FFFu + ((u >> 16) & 1u);
  return (unsigned short)(u >> 16);
}
__device__ __forceinline__ float bf2f(unsigned short h){
  return __uint_as_float(((uint32_t)h) << 16);
}

// ---------------- prep kernels ----------------

__global__ void prep_spk(const float* __restrict__ se, const float* __restrict__ We,
                         const float* __restrict__ be, const float* __restrict__ spos,
                         float* __restrict__ spk){
  int idx = blockIdx.x * 256 + threadIdx.x;   // 262144
  int sub = idx & 15; int out = idx >> 4;
  int b = out & 7, od = out >> 3;
  const float* wr = We + (size_t)od * DD + sub * 4;
  const float* sb = se + b * DD + sub * 4;
  float acc = 0.f;
#pragma unroll
  for (int i = 0; i < 8; i++){
    float4 w = *(const float4*)(wr + i * 64);
    float4 x = *(const float4*)(sb + i * 64);
    acc += w.x * x.x + w.y * x.y + w.z * x.z + w.w * x.w;
  }
  acc += __shfl_xor(acc, 1); acc += __shfl_xor(acc, 2);
  acc += __shfl_xor(acc, 4); acc += __shfl_xor(acc, 8);
  if (sub == 0) spk[b * 2048 + od] = fmaxf(acc + be[od], 0.f) + spos[od];
}

__global__ void prep_kv(const float* __restrict__ spk, const float* __restrict__ Wk,
                        const float* __restrict__ bk, const float* __restrict__ Wv,
                        const float* __restrict__ bv, float* __restrict__ kb,
                        float* __restrict__ vb){
  int idx = blockIdx.x * 256 + threadIdx.x;   // 262144
  int sub = idx & 15; int out = idx >> 4;
  int hd = out >> 5; int r = out & 31; int b = r >> 2, s = r & 3;
  const float* sp  = spk + (b * 4 + s) * DD + sub * 4;
  const float* wkr = Wk + (size_t)hd * DD + sub * 4;
  const float* wvr = Wv + (size_t)hd * DD + sub * 4;
  float ak = 0.f, av = 0.f;
#pragma unroll
  for (int i = 0; i < 8; i++){
    float4 x  = *(const float4*)(sp + i * 64);
    float4 wk = *(const float4*)(wkr + i * 64);
    float4 wv = *(const float4*)(wvr + i * 64);
    ak += x.x * wk.x + x.y * wk.y + x.z * wk.z + x.w * wk.w;
    av += x.x * wv.x + x.y * wv.y + x.z * wv.z + x.w * wv.w;
  }
  ak += __shfl_xor(ak, 1); ak += __shfl_xor(ak, 2);
  ak += __shfl_xor(ak, 4); ak += __shfl_xor(ak, 8);
  av += __shfl_xor(av, 1); av += __shfl_xor(av, 2);
  av += __shfl_xor(av, 4); av += __shfl_xor(av, 8);
  if (sub == 0){
    kb[(b * 4 + s) * DD + hd] = ak + bk[hd];
    vb[(b * 4 + s) * DD + hd] = av + bv[hd];
  }
}

// All weight operands stored LANE-MAJOR: [tile][lane][8 shorts] — the exact
// short8 each lane feeds to MFMA, so one wave-load = contiguous 1KB.
__global__ void prep_mu(const float* __restrict__ kb, const float* __restrict__ vb,
                        const float* __restrict__ Wq, const float* __restrict__ bq,
                        const float* __restrict__ Wo, const float* __restrict__ bo,
                        const float* __restrict__ Wg1,
                        const float* __restrict__ glng, const float* __restrict__ glnb,
                        const float* __restrict__ bg1,
                        unsigned short* __restrict__ mS, unsigned short* __restrict__ uS,
                        float* __restrict__ cArr, unsigned short* __restrict__ wg1S,
                        float* __restrict__ e1, float* __restrict__ e2){
  int idx = blockIdx.x * 256 + threadIdx.x;     // 328064 total
  if (idx < 131072){
    // m[b][j][d] = sum_dh Wq[h*64+dh][d] * k[b,s,h*64+dh], j = h*4+s
    int d = idx & 511; int j = (idx >> 9) & 31; int b = idx >> 14;
    int h = j >> 2, s = j & 3;
    const float* kr = kb + (b * 4 + s) * DD + h * 64;
    const float* wq = Wq + (size_t)(h * 64) * DD + d;
    float acc = 0.f;
#pragma unroll 16
    for (int dh = 0; dh < 64; dh++) acc += wq[(size_t)dh * DD] * kr[dh];
    // B-fragment lane-major store: kt = d>>5, lane = ((d>>3)&3)*16 + (j&15)
    int kt = d >> 5, kgp = (d >> 3) & 3, e = d & 7;
    int half = j >> 4;
    mS[(size_t)(b * 16 + kt) * 1024 + half * 512 + (kgp * 16 + (j & 15)) * 8 + e] = f2bf(acc);
  } else if (idx < 262144){
    // u[b][d][j] = sum_dh v[b,s,h*64+dh]*Wo[d][h*64+dh] + bo[d]/8
    int t = idx - 131072;
    int j = t & 31; int d = (t >> 5) & 511; int b = t >> 14;
    int h = j >> 2, s = j & 3;
    const float* vr = vb + (b * 4 + s) * DD + h * 64;
    const float* wo = Wo + (size_t)d * DD + h * 64;
    float acc = 0.f;
#pragma unroll 8
    for (int dh = 0; dh < 64; dh += 4){
      float4 v4 = *(const float4*)(vr + dh);
      float4 w4 = *(const float4*)(wo + dh);
      acc += v4.x * w4.x + v4.y * w4.y + v4.z * w4.z + v4.w * w4.w;
    }
    // A-fragment lane-major: nc=d>>7, nt=(d>>4)&7, lane=(j>>3)*16 + (d&15)
    int nc = d >> 7, nt = (d >> 4) & 7, r16p = d & 15;
    int kgp = j >> 3, e = j & 7;
    uS[(size_t)(b * 32 + nc * 8 + nt) * 512 + (kgp * 16 + r16p) * 8 + e] =
        f2bf(acc + bo[d] * 0.125f);
  } else if (idx < 327680){
    // wg1 (gamma-folded), B-fragment lane-major
    int t = idx - 262144;               // t = col*512 + d
    int col = t >> 9, d = t & 511;
    int nt = col >> 4, c16 = col & 15;
    int kt = d >> 5, kgp = (d >> 3) & 3, e = d & 7;
    wg1S[(size_t)(nt * 16 + kt) * 512 + (kgp * 16 + c16) * 8 + e] = f2bf(Wg1[t] * glng[d]);
  } else if (idx < 327936){
    int t = idx - 327680; int j = t & 31, b = t >> 5;
    int h = j >> 2, s = j & 3;
    const float* kr = kb + (b * 4 + s) * DD + h * 64;
    const float* bqp = bq + h * 64;
    float acc = 0.f;
    for (int dh = 0; dh < 64; dh++) acc += bqp[dh] * kr[dh];
    cArr[b * 32 + j] = acc;
  } else if (idx < 328064){
    int col = idx - 327936;
    const float* wr = Wg1 + (size_t)col * DD;
    float a1 = 0.f, a2 = 0.f;
    for (int d = 0; d < DD; d += 4){
      float4 w  = *(const float4*)(wr + d);
      float4 gm = *(const float4*)(glng + d);
      float4 bt = *(const float4*)(glnb + d);
      a1 += w.x * gm.x + w.y * gm.y + w.z * gm.z + w.w * gm.w;
      a2 += w.x * bt.x + w.y * bt.y + w.z * bt.z + w.w * bt.w;
    }
    e1[col] = a1; e2[col] = a2 + bg1[col];
  }
}

// ---------------- main fused kernel: 1 wave, 16 tokens, coalesced VMEM ----------------

__global__ __launch_bounds__(64) void fused_main(
    const float* __restrict__ xin,
    const float* __restrict__ e1v, const float* __restrict__ e2v,
    const float* __restrict__ wg2v, const float* __restrict__ bg2v,
    const float* __restrict__ lng, const float* __restrict__ lnb,
    const unsigned short* __restrict__ mS,
    const unsigned short* __restrict__ uS,
    const float* __restrict__ cArr,
    const unsigned short* __restrict__ wg1S,
    float* __restrict__ outF, float* __restrict__ outAW, float* __restrict__ outG)
{
  __shared__ __align__(16) unsigned short Yb[TT * DD];   // 16 KB: x bf16, then y bf16
  __shared__ __align__(16) unsigned short Wl[TT * 32];   // 1 KB softmax weights

  const int lane = threadIdx.x;
  const int r16 = lane & 15;
  const int kg  = lane >> 4;
  const int bb  = blockIdx.x >> 8;
  const int t0  = (blockIdx.x & 255) << 4;
  const size_t rowbase = (size_t)bb * TN + t0;
  const int swzS = (r16 & 7) << 3;   // short-index XOR swizzle for row r16

  // ---- Phase 0: fully-coalesced x load (wave reads contiguous 1KB per inst) ----
  const float* xbase = xin + rowbase * DD;
  float4 xl[32];
#pragma unroll
  for (int i = 0; i < 32; i++){
    const int r = i >> 1;
    xl[i] = *(const float4*)(xbase + r * DD + (i & 1) * 256 + lane * 4);
  }
#pragma unroll
  for (int i = 0; i < 32; i++){
    const int r = i >> 1;
    const int col = (i & 1) * 256 + lane * 4;
    short4v pk;
    pk[0] = (short)f2bf(xl[i].x); pk[1] = (short)f2bf(xl[i].y);
    pk[2] = (short)f2bf(xl[i].z); pk[3] = (short)f2bf(xl[i].w);
    *(short4v*)&Yb[r * DD + (col ^ ((r & 7) << 3))] = pk;
  }
  __syncthreads();

  // ---- read A-fragments from LDS (swizzled, conflict-free); LN stats (bf16) ----
  short8 af[16];
  float s = 0.f, q = 0.f;
#pragma unroll
  for (int kt = 0; kt < 16; kt++){
    af[kt] = *(const short8*)&Yb[r16 * DD + ((kt * 32 + kg * 8) ^ swzS)];
#pragma unroll
    for (int j = 0; j < 8; j++){
      float v = bf2f((unsigned short)af[kt][j]);
      s += v; q += v * v;
    }
  }
  s += __shfl_xor(s, 16); s += __shfl_xor(s, 32);
  q += __shfl_xor(q, 16); q += __shfl_xor(q, 32);
  const float mu = s * (1.f / DD);
  const float rs = rsqrtf(q * (1.f / DD) - mu * mu + 1e-5f);

  // ---- Phase 1: scores + gate GEMM; every weight load is contiguous 1KB ----
  const unsigned short* mSp = mS + (size_t)bb * 16384;
  f32x4 sa0 = {0.f,0.f,0.f,0.f}, sa1 = {0.f,0.f,0.f,0.f};
  f32x4 gacc[8];
#pragma unroll
  for (int nt = 0; nt < 8; nt++){ f32x4 z = {0.f,0.f,0.f,0.f}; gacc[nt] = z; }
#pragma unroll
  for (int kt = 0; kt < 16; kt++){
    short8 b0 = *(const short8*)(mSp + (size_t)kt * 1024 + lane * 8);
    short8 b1 = *(const short8*)(mSp + (size_t)kt * 1024 + 512 + lane * 8);
    sa0 = __builtin_amdgcn_mfma_f32_16x16x32_bf16(af[kt], b0, sa0, 0, 0, 0);
    sa1 = __builtin_amdgcn_mfma_f32_16x16x32_bf16(af[kt], b1, sa1, 0, 0, 0);
#pragma unroll
    for (int nt = 0; nt < 8; nt++){
      short8 wf = *(const short8*)(wg1S + (size_t)(nt * 16 + kt) * 512 + lane * 8);
      gacc[nt] = __builtin_amdgcn_mfma_f32_16x16x32_bf16(wf, af[kt], gacc[nt], 0, 0, 0);
    }
  }

  // ---- issue gate-epilogue operand loads early ----
  float4 e1c[8], e2c[8], w2c[8];
#pragma unroll
  for (int nt = 0; nt < 8; nt++){
    const int c4 = nt * 16 + kg * 4;
    e1c[nt] = *(const float4*)(e1v + c4);
    e2c[nt] = *(const float4*)(e2v + c4);
    w2c[nt] = *(const float4*)(wg2v + c4);
  }
  const float c0v  = cArr[bb * 32 + r16];
  const float c1v  = cArr[bb * 32 + r16 + 16];
  const float bg2s = bg2v[0];

  // ---- softmax epilogue: thread owns tokens kg*4+r at head-idx j = r16 ----
#pragma unroll
  for (int r = 0; r < 4; r++){
    float s0 = (sa0[r] + c0v) * 0.125f;
    float s1 = (sa1[r] + c1v) * 0.125f;
    float mx0 = fmaxf(s0, __shfl_xor(s0, 1)); mx0 = fmaxf(mx0, __shfl_xor(mx0, 2));
    float mx1 = fmaxf(s1, __shfl_xor(s1, 1)); mx1 = fmaxf(mx1, __shfl_xor(mx1, 2));
    float e0 = __expf(s0 - mx0), e1x = __expf(s1 - mx1);
    float d0 = e0;  d0 += __shfl_xor(d0, 1); d0 += __shfl_xor(d0, 2);
    float d1 = e1x; d1 += __shfl_xor(d1, 1); d1 += __shfl_xor(d1, 2);
    float w0 = e0 / d0, w1 = e1x / d1;
    float t = w0 + w1; t += __shfl_xor(t, 4); t += __shfl_xor(t, 8); t *= 0.125f;
    const int rw = kg * 4 + r;
    if ((lane & 12) == 0) outAW[(rowbase + rw) * 4 + (lane & 3)] = t;
    Wl[rw * 32 + r16]      = f2bf(w0);
    Wl[rw * 32 + r16 + 16] = f2bf(w1);
  }

  // ---- read attention-weight fragment + issue LN weight loads early ----
  short8 aw = *(const short8*)&Wl[r16 * 32 + kg * 8];
  const unsigned short* uSp = uS + (size_t)bb * 16384;
  const int c0 = lane << 3;
  float4 lgA0 = *(const float4*)(lng + c0);
  float4 lgA1 = *(const float4*)(lng + c0 + 4);
  float4 lbA0 = *(const float4*)(lnb + c0);
  float4 lbA1 = *(const float4*)(lnb + c0 + 4);

  // ---- gate epilogue: thread owns token r16 ----
  float g_reg;
  {
    float part = 0.f;
#pragma unroll
    for (int nt = 0; nt < 8; nt++){
      float e1a[4] = {e1c[nt].x, e1c[nt].y, e1c[nt].z, e1c[nt].w};
      float e2a[4] = {e2c[nt].x, e2c[nt].y, e2c[nt].z, e2c[nt].w};
      float w2a[4] = {w2c[nt].x, w2c[nt].y, w2c[nt].z, w2c[nt].w};
#pragma unroll
      for (int r = 0; r < 4; r++){
        float gv = rs * (gacc[nt][r] - mu * e1a[r]) + e2a[r];
        gv = fmaxf(gv, 0.f);
        part += gv * w2a[r];
      }
    }
    part += __shfl_xor(part, 16); part += __shfl_xor(part, 32);
    g_reg = 1.f / (1.f + __expf(-(part + bg2s)));
    if (kg == 0) outG[rowbase + r16] = g_reg;
  }

  // ---- phase 3: ATT + residual (x from Yb), y back into Yb ----
  float psum = 0.f, psq = 0.f;
#pragma unroll
  for (int nc = 0; nc < 4; nc++){
    f32x4 acc[8];
#pragma unroll
    for (int nt = 0; nt < 8; nt++){
      short8 uf = *(const short8*)(uSp + (size_t)(nc * 8 + nt) * 512 + lane * 8);
      f32x4 z = {0.f,0.f,0.f,0.f};
      acc[nt] = __builtin_amdgcn_mfma_f32_16x16x32_bf16(uf, aw, z, 0, 0, 0);
    }
#pragma unroll
    for (int nt = 0; nt < 8; nt++){
      const int idx = r16 * DD + ((nc * 128 + nt * 16 + kg * 4) ^ swzS);
      uint2v xch = *(const uint2v*)&Yb[idx];
      unsigned int lo = xch[0], hi = xch[1];
      float y0 = bf2f((unsigned short)(lo & 0xffffu)) + g_reg * acc[nt][0];
      float y1 = bf2f((unsigned short)(lo >> 16))     + g_reg * acc[nt][1];
      float y2 = bf2f((unsigned short)(hi & 0xffffu)) + g_reg * acc[nt][2];
      float y3 = bf2f((unsigned short)(hi >> 16))     + g_reg * acc[nt][3];
      psum += (y0 + y1) + (y2 + y3);
      psq  += (y0 * y0 + y1 * y1) + (y2 * y2 + y3 * y3);
      uint2v yp;
      yp[0] = (unsigned)f2bf(y0) | ((unsigned)f2bf(y1) << 16);
      yp[1] = (unsigned)f2bf(y2) | ((unsigned)f2bf(y3) << 16);
      *(uint2v*)&Yb[idx] = yp;
    }
  }

  // ---- final-LN stats ----
  psum += __shfl_xor(psum, 16); psum += __shfl_xor(psum, 32);
  psq  += __shfl_xor(psq, 16);  psq  += __shfl_xor(psq, 32);
  const float mu2 = psum * (1.f / DD);
  const float rs2 = rsqrtf(psq * (1.f / DD) - mu2 * mu2 + 1e-5f);

  // ---- phase 4: final LN + contiguous fp32 row stores ----
  float lg[8]  = {lgA0.x, lgA0.y, lgA0.z, lgA0.w, lgA1.x, lgA1.y, lgA1.z, lgA1.w};
  float lb8[8] = {lbA0.x, lbA0.y, lbA0.z, lbA0.w, lbA1.x, lbA1.y, lbA1.z, lbA1.w};
#pragma unroll
  for (int r = 0; r < TT; r++){
    const float m2  = __shfl(mu2, r);
    const float r2v = __shfl(rs2, r);
    short8 yv = *(const short8*)&Yb[r * DD + (c0 ^ ((r & 7) << 3))];
    float o[8];
#pragma unroll
    for (int j = 0; j < 8; j++)
      o[j] = (bf2f((unsigned short)yv[j]) - m2) * r2v * lg[j] + lb8[j];
    float* op = outF + (rowbase + r) * DD + c0;
    float4 o0; o0.x = o[0]; o0.y = o[1]; o0.z = o[2]; o0.w = o[3];
    float4 o1; o1.x = o[4]; o1.y = o[5]; o1.z = o[6]; o1.w = o[7];
    *(float4*)op = o0;
    *(float4*)(op + 4) = o1;
  }
}

// ---------------- launch ----------------

extern "C" void kernel_launch(void* const* d_in, const int* in_sizes, int n_in,
                              void* d_out, int out_size, void* d_ws, size_t ws_size,
                              hipStream_t stream)
{
  const float* token = (const float*)d_in[0];
  const float* semb  = (const float*)d_in[1];
  const float* We    = (const float*)d_in[2];
  const float* be    = (const float*)d_in[3];
  const float* spos  = (const float*)d_in[4];
  const float* Wq    = (const float*)d_in[5];
  const float* bq    = (const float*)d_in[6];
  const float* Wk    = (const float*)d_in[7];
  const float* bk    = (const float*)d_in[8];
  const float* Wv    = (const float*)d_in[9];
  const float* bv    = (const float*)d_in[10];
  const float* Wo    = (const float*)d_in[11];
  const float* bo    = (const float*)d_in[12];
  const float* glng  = (const float*)d_in[13];
  const float* glnb  = (const float*)d_in[14];
  const float* Wg1   = (const float*)d_in[15];
  const float* bg1   = (const float*)d_in[16];
  const float* Wg2   = (const float*)d_in[17];
  const float* bg2   = (const float*)d_in[18];
  const float* lng   = (const float*)d_in[19];
  const float* lnb   = (const float*)d_in[20];

  char* ws = (char*)d_ws;
  float* e1             = (float*)(ws + 0);        // 512 B (spk region reused)
  float* e2             = (float*)(ws + 512);
  float* spk            = (float*)(ws + 0);        // 64 KB (dead before e1/e2 written)
  float* kb             = (float*)(ws + 65536);
  float* vb             = (float*)(ws + 131072);
  unsigned short* mS    = (unsigned short*)(ws + 196608);
  unsigned short* uS    = (unsigned short*)(ws + 458752);
  float* cArr           = (float*)(ws + 720896);
  unsigned short* wg1S  = (unsigned short*)(ws + 721920);

  float* outF  = (float*)d_out;
  float* outAW = outF + (size_t)NB * TN * DD;
  float* outG  = outAW + (size_t)NB * TN * 4;

  prep_spk<<<dim3(1024), dim3(256), 0, stream>>>(semb, We, be, spos, spk);
  prep_kv<<<dim3(1024), dim3(256), 0, stream>>>(spk, Wk, bk, Wv, bv, kb, vb);
  prep_mu<<<dim3(1282), dim3(256), 0, stream>>>(kb, vb, Wq, bq, Wo, bo, Wg1, glng, glnb, bg1,
                                                mS, uS, cArr, wg1S, e1, e2);
  fused_main<<<dim3(NB * TN / TT), dim3(64), 0, stream>>>(
      token, e1, e2, Wg2, bg2, lng, lnb,
      mS, uS, cArr, wg1S, outF, outAW, outG);
}